// Round 5
// baseline (186.398 us; speedup 1.0000x reference)
//
#include <hip/hip_runtime.h>
#include <math.h>

// EdgeConditionedConv on MI355X — round 4: raise edge_msg occupancy 2->3
// blocks/CU by cutting live registers: gv folded into B operand (f16 pk_mul)
// so MFMA accumulates straight into msg (P tile + f32 epilogue eliminated);
// A fragments loaded per-ks instead of all-upfront.

constexpr int N_NODES  = 25000;
constexpr int N_EDGES  = 50000;
constexpr int NODE_DIM = 64;
constexpr int EDGE_DIM = 16;
constexpr int HID      = 128;

typedef __attribute__((ext_vector_type(8))) _Float16 half8;
typedef __attribute__((ext_vector_type(2))) _Float16 half2v;
typedef __attribute__((ext_vector_type(4))) float    f32x4;

// ---------------------------------------------------------------- prepack
__global__ __launch_bounds__(256) void prepack_kernel(
    const float* __restrict__ W2, const float* __restrict__ b2,
    const float* __restrict__ w_ih, const float* __restrict__ w_hh,
    _Float16* __restrict__ Wpk, _Float16* __restrict__ b2pk,
    float* __restrict__ wTih, float* __restrict__ wThh)
{
    int c = blockIdx.x * 256 + threadIdx.x;
    if (c < 65536) {
        int lane = c & 63, mt = (c >> 6) & 3, ks = (c >> 8) & 3, j = c >> 10;
        int i   = mt * 16 + (lane & 15);
        int col = ks * 32 + ((lane >> 4) & 3) * 8;
        const float* src = W2 + (size_t)(i * 64 + j) * HID + col;
        half8 o;
#pragma unroll
        for (int q = 0; q < 8; ++q) o[q] = (_Float16)src[q];
        ((half8*)Wpk)[c] = o;
    } else if (c < 65536 + 512) {
        int c2 = c - 65536;
        int lane = c2 & 63, mt = (c2 >> 6) & 3, ks2 = (c2 >> 8) & 1;
        int i = mt * 16 + (lane & 15);
        int j = ks2 * 32 + ((lane >> 4) & 3) * 8;
        const float* src = b2 + i * 64 + j;
        half8 o;
#pragma unroll
        for (int q = 0; q < 8; ++q) o[q] = (_Float16)src[q];
        ((half8*)b2pk)[c2] = o;
    } else if (c < 65536 + 512 + 2 * 12288) {
        int idx = c - (65536 + 512);
        const float* src = (idx < 12288) ? w_ih : w_hh;
        float*       dst = (idx < 12288) ? wTih : wThh;
        int e2 = (idx < 12288) ? idx : idx - 12288;
        int k = e2 / 192, g = e2 - k * 192;
        dst[k * 192 + g] = src[(size_t)g * 64 + k];
    }
}

// ---------------------------------------------------------------- phase 1
__global__ __launch_bounds__(256) void edge_mlp1_kernel(
    const float* __restrict__ edge_attr,
    const float* __restrict__ W1,
    const float* __restrict__ b1,
    _Float16* __restrict__ h)
{
    int e = blockIdx.x * 2 + (threadIdx.x >> 7);
    int k = threadIdx.x & 127;
    if (e >= N_EDGES) return;
    const float* ea = edge_attr + (size_t)e * EDGE_DIM;
    const float* w  = W1 + (size_t)k * EDGE_DIM;
    float acc = b1[k];
#pragma unroll
    for (int d = 0; d < EDGE_DIM; ++d) acc += ea[d] * w[d];
    float g = 0.5f * acc * (1.0f + erff(acc * 0.70710678118654752f));
    h[(size_t)e * HID + k] = (_Float16)g;
}

// ---------------------------------------------------------------- phase 2
__global__ __launch_bounds__(256, 3) void edge_msg_mfma_kernel(
    const _Float16* __restrict__ hbuf,
    const float*    __restrict__ x,
    const int*      __restrict__ edge_index,   // [2][E] int32
    const _Float16* __restrict__ Wpk,
    const _Float16* __restrict__ b2pk,
    float* __restrict__ agg)                   // [N][64], pre-zeroed
{
    __shared__ float xsh[64 * 68];      // gathered x[src], pitch 68
    __shared__ float msgred[64 * 67];   // [i][e], pitch 67
    __shared__ int   dsts[64];

    const int e0   = blockIdx.x * 64;
    const int t    = threadIdx.x;
    const int wave = t >> 6;
    const int lane = t & 63;

    // ---- gather x[src[e]] rows into xsh (zero-fill invalid) + dsts
    {
        int le = t >> 2, sub = t & 3;
        int e = e0 + le;
        int s = -1;
        if (e < N_EDGES) {
            if (sub == 0) dsts[le] = edge_index[N_EDGES + e];
            s = edge_index[e];
        } else if (sub == 0) {
            dsts[le] = -1;
        }
#pragma unroll
        for (int q = 0; q < 4; ++q) {
            float4 v = make_float4(0.f, 0.f, 0.f, 0.f);
            if ((unsigned)s < (unsigned)N_NODES)
                v = ((const float4*)x)[(size_t)s * 16 + sub * 4 + q];
            *(float4*)&xsh[le * 68 + sub * 16 + q * 4] = v;
        }
    }

    // ---- per-wave resident h fragments (B operand), f16
    half8 hf[4][4];   // [nt][ks]
#pragma unroll
    for (int nt = 0; nt < 4; ++nt) {
#pragma unroll
        for (int ks = 0; ks < 4; ++ks) {
            int el = nt * 16 + (lane & 15);
            int ee = e0 + el; if (ee >= N_EDGES) ee = N_EDGES - 1;
            int gk = ks * 32 + ((lane >> 4) & 3) * 8;
            hf[nt][ks] = *(const half8*)(hbuf + (size_t)ee * HID + gk);
        }
    }
    __syncthreads();

    const f32x4 zero4 = {0.f, 0.f, 0.f, 0.f};
    f32x4 msg[4][4];  // [mt][nt]
#pragma unroll
    for (int mt = 0; mt < 4; ++mt)
#pragma unroll
        for (int nt = 0; nt < 4; ++nt) msg[mt][nt] = zero4;

    const half8* wpk8 = (const half8*)Wpk;

    // ---- main loop: this wave handles j = wave*16 .. wave*16+15
    // msg[mt][nt] += A(W2 frag, j) * (hf[nt] * gv[nt](j))   (gv folded into B)
#pragma unroll 1
    for (int jj = 0; jj < 16; ++jj) {
        int j = wave * 16 + jj;
        half2v gvp[4];
#pragma unroll
        for (int nt = 0; nt < 4; ++nt) {
            _Float16 gh = (_Float16)xsh[(nt * 16 + (lane & 15)) * 68 + j];
            half2v p; p[0] = gh; p[1] = gh;
            gvp[nt] = p;
        }

        size_t base = (size_t)j * 1024 + lane;
#pragma unroll
        for (int ks = 0; ks < 4; ++ks) {
            half8 a[4];
#pragma unroll
            for (int mt = 0; mt < 4; ++mt) a[mt] = wpk8[base + ks * 256 + mt * 64];
#pragma unroll
            for (int nt = 0; nt < 4; ++nt) {
                // hsc = hf[nt][ks] * gv  (packed f16, 4x half2)
                half8 hsc;
                half2v* hd = (half2v*)&hsc;
                const half2v* hs = (const half2v*)&hf[nt][ks];
#pragma unroll
                for (int q = 0; q < 4; ++q) hd[q] = hs[q] * gvp[nt];
#pragma unroll
                for (int mt = 0; mt < 4; ++mt)
                    msg[mt][nt] = __builtin_amdgcn_mfma_f32_16x16x32_f16(
                        a[mt], hsc, msg[mt][nt], 0, 0, 0);
            }
        }
    }

    // ---- bias term (wave 0 only): msg[i,e] += sum_j b2[i*64+j]*g[e,j]
    if (wave == 0) {
#pragma unroll
        for (int ks2 = 0; ks2 < 2; ++ks2) {
            half8 gf[4];
#pragma unroll
            for (int nt = 0; nt < 4; ++nt) {
                const float* gp = &xsh[(nt * 16 + (lane & 15)) * 68 + ks2 * 32 + ((lane >> 4) & 3) * 8];
                float4 lo = *(const float4*)gp;
                float4 hi = *(const float4*)(gp + 4);
                half8 g8;
                g8[0] = (_Float16)lo.x; g8[1] = (_Float16)lo.y;
                g8[2] = (_Float16)lo.z; g8[3] = (_Float16)lo.w;
                g8[4] = (_Float16)hi.x; g8[5] = (_Float16)hi.y;
                g8[6] = (_Float16)hi.z; g8[7] = (_Float16)hi.w;
                gf[nt] = g8;
            }
#pragma unroll
            for (int mt = 0; mt < 4; ++mt) {
                half8 bf8 = ((const half8*)b2pk)[ks2 * 256 + mt * 64 + lane];
#pragma unroll
                for (int nt = 0; nt < 4; ++nt)
                    msg[mt][nt] = __builtin_amdgcn_mfma_f32_16x16x32_f16(
                        bf8, gf[nt], msg[mt][nt], 0, 0, 0);
            }
        }
    }

    // ---- cross-wave reduce into msgred[i][e]
    if (wave == 0) {
#pragma unroll
        for (int mt = 0; mt < 4; ++mt)
#pragma unroll
            for (int nt = 0; nt < 4; ++nt)
#pragma unroll
                for (int r = 0; r < 4; ++r) {
                    int i = mt * 16 + ((lane >> 4) & 3) * 4 + r;
                    int e = nt * 16 + (lane & 15);
                    msgred[i * 67 + e] = msg[mt][nt][r];
                }
    }
    __syncthreads();
#pragma unroll 1
    for (int w = 1; w < 4; ++w) {
        if (wave == w) {
#pragma unroll
            for (int mt = 0; mt < 4; ++mt)
#pragma unroll
                for (int nt = 0; nt < 4; ++nt)
#pragma unroll
                    for (int r = 0; r < 4; ++r) {
                        int i = mt * 16 + ((lane >> 4) & 3) * 4 + r;
                        int e = nt * 16 + (lane & 15);
                        msgred[i * 67 + e] += msg[mt][nt][r];
                    }
        }
        __syncthreads();
    }

    // ---- scatter, coalesced: one edge row per atomic instr (lane = dim i)
    {
#pragma unroll 1
        for (int ee = wave; ee < 64; ee += 4) {
            int d = dsts[ee];
            if (e0 + ee < N_EDGES && (unsigned)d < (unsigned)N_NODES)
                atomicAdd(agg + (size_t)d * NODE_DIM + lane, msgred[lane * 67 + ee]);
        }
    }
}

// ---------------------------------------------------------------- phase 3
__global__ __launch_bounds__(256) void gru_kernel(
    const float* __restrict__ agg,
    const float* __restrict__ x,
    const float* __restrict__ wTih,   // [64][192]
    const float* __restrict__ wThh,   // [64][192]
    const float* __restrict__ b_ih,
    const float* __restrict__ b_hh,
    float* __restrict__ out)
{
    __shared__ float as_[32][64], xs_[32][64];
    const int t    = threadIdx.x;
    const int wave = t >> 6, lane = t & 63;
    const int n0   = blockIdx.x * 32;

    {
        const float4* asrc = (const float4*)(agg + (size_t)n0 * 64);
        const float4* xsrc = (const float4*)(x   + (size_t)n0 * 64);
        float4* ad = (float4*)&as_[0][0];
        float4* xd = (float4*)&xs_[0][0];
        int nvalid4 = min(N_NODES - n0, 32) * 16;
#pragma unroll
        for (int r = 0; r < 2; ++r) {
            int idx = t + r * 256;
            float4 v = make_float4(0.f, 0.f, 0.f, 0.f), u = v;
            if (idx < nvalid4) { v = asrc[idx]; u = xsrc[idx]; }
            ad[idx] = v; xd[idx] = u;
        }
    }
    __syncthreads();

    float accI0[8] = {}, accI1[8] = {}, accI2[8] = {};
    float accH0[8] = {}, accH1[8] = {}, accH2[8] = {};

#pragma unroll 4
    for (int k = 0; k < 64; ++k) {
        float wi0 = wTih[k * 192 + lane];
        float wi1 = wTih[k * 192 + 64 + lane];
        float wi2 = wTih[k * 192 + 128 + lane];
        float wh0 = wThh[k * 192 + lane];
        float wh1 = wThh[k * 192 + 64 + lane];
        float wh2 = wThh[k * 192 + 128 + lane];
#pragma unroll
        for (int n = 0; n < 8; ++n) {
            float a  = as_[wave * 8 + n][k];
            float xx = xs_[wave * 8 + n][k];
            accI0[n] += a * wi0;  accI1[n] += a * wi1;  accI2[n] += a * wi2;
            accH0[n] += xx * wh0; accH1[n] += xx * wh1; accH2[n] += xx * wh2;
        }
    }

    float bi0 = b_ih[lane], bi1 = b_ih[64 + lane], bi2 = b_ih[128 + lane];
    float bh0 = b_hh[lane], bh1 = b_hh[64 + lane], bh2 = b_hh[128 + lane];
#pragma unroll
    for (int n = 0; n < 8; ++n) {
        int node = n0 + wave * 8 + n;
        if (node >= N_NODES) break;
        float r  = 1.f / (1.f + expf(-(accI0[n] + bi0 + accH0[n] + bh0)));
        float z  = 1.f / (1.f + expf(-(accI1[n] + bi1 + accH1[n] + bh1)));
        float nn = tanhf(accI2[n] + bi2 + r * (accH2[n] + bh2));
        out[(size_t)node * 64 + lane] = (1.f - z) * nn + z * xs_[wave * 8 + n][lane];
    }
}

// ---------------------------------------------------------------- launch
extern "C" void kernel_launch(void* const* d_in, const int* in_sizes, int n_in,
                              void* d_out, int out_size, void* d_ws, size_t ws_size,
                              hipStream_t stream)
{
    const float* x          = (const float*)d_in[0];
    const int*   edge_index = (const int*)  d_in[1];
    const float* edge_attr  = (const float*)d_in[2];
    const float* W1         = (const float*)d_in[3];
    const float* b1         = (const float*)d_in[4];
    const float* W2         = (const float*)d_in[5];
    const float* b2         = (const float*)d_in[6];
    const float* w_ih       = (const float*)d_in[7];
    const float* w_hh       = (const float*)d_in[8];
    const float* b_ih       = (const float*)d_in[9];
    const float* b_hh       = (const float*)d_in[10];
    float* out = (float*)d_out;

    char* ws = (char*)d_ws;
    _Float16* hbuf = (_Float16*)ws;                         // 12.8 MB
    ws += (size_t)N_EDGES * HID * sizeof(_Float16);
    _Float16* Wpk  = (_Float16*)ws;                         // 1 MB
    ws += (size_t)65536 * 8 * sizeof(_Float16);
    _Float16* b2pk = (_Float16*)ws;                         // 8 KB
    ws += (size_t)512 * 8 * sizeof(_Float16);
    float* wTih = (float*)ws;                               // 48 KB
    ws += (size_t)64 * 192 * sizeof(float);
    float* wThh = (float*)ws;                               // 48 KB
    ws += (size_t)64 * 192 * sizeof(float);
    float* agg = (float*)ws;                                // 6.4 MB

    hipMemsetAsync(agg, 0, (size_t)N_NODES * NODE_DIM * sizeof(float), stream);

    prepack_kernel<<<dim3(355), dim3(256), 0, stream>>>(
        W2, b2, w_ih, w_hh, Wpk, b2pk, wTih, wThh);

    edge_mlp1_kernel<<<dim3(N_EDGES / 2), dim3(256), 0, stream>>>(edge_attr, W1, b1, hbuf);

    edge_msg_mfma_kernel<<<dim3((N_EDGES + 63) / 64), dim3(256), 0, stream>>>(
        hbuf, x, edge_index, Wpk, b2pk, agg);

    gru_kernel<<<dim3((N_NODES + 31) / 32), dim3(256), 0, stream>>>(
        agg, x, wTih, wThh, b_ih, b_hh, out);
}

// Round 6
// 157.122 us; speedup vs baseline: 1.1863x; 1.1863x over previous
//
#include <hip/hip_runtime.h>
#include <math.h>

// EdgeConditionedConv on MI355X — round 5:
// (a) edge_msg restructured: wave = output-row block (mt), all j per wave ->
//     small accumulators, 2-deep register prefetch of W2 fragments hides L2
//     latency (round-4 null showed latency, not regs, was the stall);
//     no cross-wave reduce; gv epilogue back in f32.
// (b) memset+prepack+mlp1 merged into one prep kernel (5 -> 3 launches).

constexpr int N_NODES  = 25000;
constexpr int N_EDGES  = 50000;
constexpr int NODE_DIM = 64;
constexpr int EDGE_DIM = 16;
constexpr int HID      = 128;

typedef __attribute__((ext_vector_type(8))) _Float16 half8;
typedef __attribute__((ext_vector_type(4))) float    f32x4;

constexpr int G_MS  = 128;             // agg-zero blocks
constexpr int G_PK  = 355;             // prepack blocks (355*256 >= 90624)
constexpr int G_MLP = N_EDGES / 2;     // mlp1 blocks (2 edges each)

// ---------------------------------------------------------------- prep
// blockIdx ranges: [0,G_MS) zero agg | [G_MS,G_MS+G_PK) prepack | rest mlp1
__global__ __launch_bounds__(256) void prep_kernel(
    const float* __restrict__ W2, const float* __restrict__ b2,
    const float* __restrict__ w_ih, const float* __restrict__ w_hh,
    const float* __restrict__ edge_attr, const float* __restrict__ W1,
    const float* __restrict__ b1,
    _Float16* __restrict__ Wpk, _Float16* __restrict__ b2pk,
    float* __restrict__ wTih, float* __restrict__ wThh,
    _Float16* __restrict__ h, float* __restrict__ agg)
{
    int b = blockIdx.x;
    if (b < G_MS) {
        // zero agg (needed before atomics, every replay)
        float4* a4 = (float4*)agg;
        const float4 z = make_float4(0.f, 0.f, 0.f, 0.f);
        for (int i = b * 256 + threadIdx.x; i < N_NODES * NODE_DIM / 4; i += G_MS * 256)
            a4[i] = z;
        return;
    }
    if (b < G_MS + G_PK) {
        int c = (b - G_MS) * 256 + threadIdx.x;
        if (c < 65536) {
            int lane = c & 63, mt = (c >> 6) & 3, ks = (c >> 8) & 3, j = c >> 10;
            int i   = mt * 16 + (lane & 15);
            int col = ks * 32 + ((lane >> 4) & 3) * 8;
            const float* src = W2 + (size_t)(i * 64 + j) * HID + col;
            half8 o;
#pragma unroll
            for (int q = 0; q < 8; ++q) o[q] = (_Float16)src[q];
            ((half8*)Wpk)[c] = o;
        } else if (c < 65536 + 512) {
            int c2 = c - 65536;
            int lane = c2 & 63, mt = (c2 >> 6) & 3, ks2 = (c2 >> 8) & 1;
            int i = mt * 16 + (lane & 15);
            int j = ks2 * 32 + ((lane >> 4) & 3) * 8;
            const float* src = b2 + i * 64 + j;
            half8 o;
#pragma unroll
            for (int q = 0; q < 8; ++q) o[q] = (_Float16)src[q];
            ((half8*)b2pk)[c2] = o;
        } else if (c < 65536 + 512 + 2 * 12288) {
            int idx = c - (65536 + 512);
            const float* src = (idx < 12288) ? w_ih : w_hh;
            float*       dst = (idx < 12288) ? wTih : wThh;
            int e2 = (idx < 12288) ? idx : idx - 12288;
            int k = e2 / 192, g = e2 - k * 192;
            dst[k * 192 + g] = src[(size_t)g * 64 + k];
        }
        return;
    }
    // mlp1: h[e,k] = gelu(edge_attr[e,:].W1[k,:] + b1[k]) -> f16
    int e = (b - G_MS - G_PK) * 2 + (threadIdx.x >> 7);
    int k = threadIdx.x & 127;
    if (e >= N_EDGES) return;
    const float* ea = edge_attr + (size_t)e * EDGE_DIM;
    const float* w  = W1 + (size_t)k * EDGE_DIM;
    float acc = b1[k];
#pragma unroll
    for (int d = 0; d < EDGE_DIM; ++d) acc += ea[d] * w[d];
    float g = 0.5f * acc * (1.0f + erff(acc * 0.70710678118654752f));
    h[(size_t)e * HID + k] = (_Float16)g;
}

// ---------------------------------------------------------------- phase 2
// Wave w owns output rows i in [w*16, w*16+16) for ALL j (no cross-wave
// reduce). Per j: 4 prefetched A-loads, 16 MFMA into P, f32 gv epilogue.
__global__ __launch_bounds__(256, 3) void edge_msg_mfma_kernel(
    const _Float16* __restrict__ hbuf,
    const float*    __restrict__ x,
    const int*      __restrict__ edge_index,   // [2][E] int32
    const _Float16* __restrict__ Wpk,
    const _Float16* __restrict__ b2pk,
    float* __restrict__ agg)                   // [N][64], pre-zeroed
{
    __shared__ float xsh[64 * 68];      // gathered x[src], pitch 68
    __shared__ float msgred[64 * 67];   // [i][e], pitch 67
    __shared__ int   dsts[64];

    const int e0   = blockIdx.x * 64;
    const int t    = threadIdx.x;
    const int mt   = t >> 6;            // wave = output row block
    const int lane = t & 63;

    // ---- gather x[src[e]] rows into xsh (zero-fill invalid) + dsts
    {
        int le = t >> 2, sub = t & 3;
        int e = e0 + le;
        int s = -1;
        if (e < N_EDGES) {
            if (sub == 0) dsts[le] = edge_index[N_EDGES + e];
            s = edge_index[e];
        } else if (sub == 0) {
            dsts[le] = -1;
        }
#pragma unroll
        for (int q = 0; q < 4; ++q) {
            float4 v = make_float4(0.f, 0.f, 0.f, 0.f);
            if ((unsigned)s < (unsigned)N_NODES)
                v = ((const float4*)x)[(size_t)s * 16 + sub * 4 + q];
            *(float4*)&xsh[le * 68 + sub * 16 + q * 4] = v;
        }
    }

    // ---- per-wave resident h fragments (B operand, same in all waves)
    half8 hf[4][4];   // [nt][ks]
#pragma unroll
    for (int nt = 0; nt < 4; ++nt) {
#pragma unroll
        for (int ks = 0; ks < 4; ++ks) {
            int el = nt * 16 + (lane & 15);
            int ee = e0 + el; if (ee >= N_EDGES) ee = N_EDGES - 1;
            int gk = ks * 32 + ((lane >> 4) & 3) * 8;
            hf[nt][ks] = *(const half8*)(hbuf + (size_t)ee * HID + gk);
        }
    }
    __syncthreads();

    const f32x4 zero4 = {0.f, 0.f, 0.f, 0.f};
    f32x4 msg[4];     // [nt]
#pragma unroll
    for (int nt = 0; nt < 4; ++nt) msg[nt] = zero4;

    const half8* wpk8 = (const half8*)Wpk;
    const int mbase = mt * 64 + lane;

    half8 aA[4], aB[4];
#pragma unroll
    for (int ks = 0; ks < 4; ++ks) aA[ks] = wpk8[(size_t)mbase + ks * 256];  // j=0

#pragma unroll 1
    for (int j = 0; j < 64; j += 2) {
        // prefetch j+1
        {
            size_t nb = (size_t)(j + 1) * 1024 + mbase;
#pragma unroll
            for (int ks = 0; ks < 4; ++ks) aB[ks] = wpk8[nb + ks * 256];
        }
        // compute j with aA
        {
            float gv[4];
#pragma unroll
            for (int nt = 0; nt < 4; ++nt) gv[nt] = xsh[(nt * 16 + (lane & 15)) * 68 + j];
            f32x4 P[4];
#pragma unroll
            for (int ks = 0; ks < 4; ++ks)
#pragma unroll
                for (int nt = 0; nt < 4; ++nt)
                    P[nt] = __builtin_amdgcn_mfma_f32_16x16x32_f16(
                        aA[ks], hf[nt][ks], ks == 0 ? zero4 : P[nt], 0, 0, 0);
#pragma unroll
            for (int nt = 0; nt < 4; ++nt)
#pragma unroll
                for (int r = 0; r < 4; ++r) msg[nt][r] += gv[nt] * P[nt][r];
        }
        // prefetch j+2
        if (j + 2 < 64) {
            size_t nb = (size_t)(j + 2) * 1024 + mbase;
#pragma unroll
            for (int ks = 0; ks < 4; ++ks) aA[ks] = wpk8[nb + ks * 256];
        }
        // compute j+1 with aB
        {
            float gv[4];
#pragma unroll
            for (int nt = 0; nt < 4; ++nt) gv[nt] = xsh[(nt * 16 + (lane & 15)) * 68 + j + 1];
            f32x4 P[4];
#pragma unroll
            for (int ks = 0; ks < 4; ++ks)
#pragma unroll
                for (int nt = 0; nt < 4; ++nt)
                    P[nt] = __builtin_amdgcn_mfma_f32_16x16x32_f16(
                        aB[ks], hf[nt][ks], ks == 0 ? zero4 : P[nt], 0, 0, 0);
#pragma unroll
            for (int nt = 0; nt < 4; ++nt)
#pragma unroll
                for (int r = 0; r < 4; ++r) msg[nt][r] += gv[nt] * P[nt][r];
        }
    }

    // ---- bias for this wave's rows: msg[i,e] += sum_j b2[i*64+j]*g[e,j]
#pragma unroll
    for (int ks2 = 0; ks2 < 2; ++ks2) {
        half8 gf[4];
#pragma unroll
        for (int nt = 0; nt < 4; ++nt) {
            const float* gp = &xsh[(nt * 16 + (lane & 15)) * 68 + ks2 * 32 + ((lane >> 4) & 3) * 8];
            float4 lo = *(const float4*)gp;
            float4 hi = *(const float4*)(gp + 4);
            half8 g8;
            g8[0] = (_Float16)lo.x; g8[1] = (_Float16)lo.y;
            g8[2] = (_Float16)lo.z; g8[3] = (_Float16)lo.w;
            g8[4] = (_Float16)hi.x; g8[5] = (_Float16)hi.y;
            g8[6] = (_Float16)hi.z; g8[7] = (_Float16)hi.w;
            gf[nt] = g8;
        }
        half8 bf8 = ((const half8*)b2pk)[ks2 * 256 + mt * 64 + lane];
#pragma unroll
        for (int nt = 0; nt < 4; ++nt)
            msg[nt] = __builtin_amdgcn_mfma_f32_16x16x32_f16(bf8, gf[nt], msg[nt], 0, 0, 0);
    }

    // ---- each wave writes its exclusive 16 rows of msgred
#pragma unroll
    for (int nt = 0; nt < 4; ++nt)
#pragma unroll
        for (int r = 0; r < 4; ++r) {
            int i = mt * 16 + ((lane >> 4) & 3) * 4 + r;
            int e = nt * 16 + (lane & 15);
            msgred[i * 67 + e] = msg[nt][r];
        }
    __syncthreads();

    // ---- scatter, coalesced: one edge row per atomic instr (lane = dim i)
#pragma unroll 1
    for (int ee = mt; ee < 64; ee += 4) {
        int d = dsts[ee];
        if (e0 + ee < N_EDGES && (unsigned)d < (unsigned)N_NODES)
            atomicAdd(agg + (size_t)d * NODE_DIM + lane, msgred[lane * 67 + ee]);
    }
}

// ---------------------------------------------------------------- phase 3
__global__ __launch_bounds__(256) void gru_kernel(
    const float* __restrict__ agg,
    const float* __restrict__ x,
    const float* __restrict__ wTih,   // [64][192]
    const float* __restrict__ wThh,   // [64][192]
    const float* __restrict__ b_ih,
    const float* __restrict__ b_hh,
    float* __restrict__ out)
{
    __shared__ float as_[32][64], xs_[32][64];
    const int t    = threadIdx.x;
    const int wave = t >> 6, lane = t & 63;
    const int n0   = blockIdx.x * 32;

    {
        const float4* asrc = (const float4*)(agg + (size_t)n0 * 64);
        const float4* xsrc = (const float4*)(x   + (size_t)n0 * 64);
        float4* ad = (float4*)&as_[0][0];
        float4* xd = (float4*)&xs_[0][0];
        int nvalid4 = min(N_NODES - n0, 32) * 16;
#pragma unroll
        for (int r = 0; r < 2; ++r) {
            int idx = t + r * 256;
            float4 v = make_float4(0.f, 0.f, 0.f, 0.f), u = v;
            if (idx < nvalid4) { v = asrc[idx]; u = xsrc[idx]; }
            ad[idx] = v; xd[idx] = u;
        }
    }
    __syncthreads();

    float accI0[8] = {}, accI1[8] = {}, accI2[8] = {};
    float accH0[8] = {}, accH1[8] = {}, accH2[8] = {};

#pragma unroll 4
    for (int k = 0; k < 64; ++k) {
        float wi0 = wTih[k * 192 + lane];
        float wi1 = wTih[k * 192 + 64 + lane];
        float wi2 = wTih[k * 192 + 128 + lane];
        float wh0 = wThh[k * 192 + lane];
        float wh1 = wThh[k * 192 + 64 + lane];
        float wh2 = wThh[k * 192 + 128 + lane];
#pragma unroll
        for (int n = 0; n < 8; ++n) {
            float a  = as_[wave * 8 + n][k];
            float xx = xs_[wave * 8 + n][k];
            accI0[n] += a * wi0;  accI1[n] += a * wi1;  accI2[n] += a * wi2;
            accH0[n] += xx * wh0; accH1[n] += xx * wh1; accH2[n] += xx * wh2;
        }
    }

    float bi0 = b_ih[lane], bi1 = b_ih[64 + lane], bi2 = b_ih[128 + lane];
    float bh0 = b_hh[lane], bh1 = b_hh[64 + lane], bh2 = b_hh[128 + lane];
#pragma unroll
    for (int n = 0; n < 8; ++n) {
        int node = n0 + wave * 8 + n;
        if (node >= N_NODES) break;
        float r  = 1.f / (1.f + expf(-(accI0[n] + bi0 + accH0[n] + bh0)));
        float z  = 1.f / (1.f + expf(-(accI1[n] + bi1 + accH1[n] + bh1)));
        float nn = tanhf(accI2[n] + bi2 + r * (accH2[n] + bh2));
        out[(size_t)node * 64 + lane] = (1.f - z) * nn + z * xs_[wave * 8 + n][lane];
    }
}

// ---------------------------------------------------------------- launch
extern "C" void kernel_launch(void* const* d_in, const int* in_sizes, int n_in,
                              void* d_out, int out_size, void* d_ws, size_t ws_size,
                              hipStream_t stream)
{
    const float* x          = (const float*)d_in[0];
    const int*   edge_index = (const int*)  d_in[1];
    const float* edge_attr  = (const float*)d_in[2];
    const float* W1         = (const float*)d_in[3];
    const float* b1         = (const float*)d_in[4];
    const float* W2         = (const float*)d_in[5];
    const float* b2         = (const float*)d_in[6];
    const float* w_ih       = (const float*)d_in[7];
    const float* w_hh       = (const float*)d_in[8];
    const float* b_ih       = (const float*)d_in[9];
    const float* b_hh       = (const float*)d_in[10];
    float* out = (float*)d_out;

    char* ws = (char*)d_ws;
    _Float16* hbuf = (_Float16*)ws;                         // 12.8 MB
    ws += (size_t)N_EDGES * HID * sizeof(_Float16);
    _Float16* Wpk  = (_Float16*)ws;                         // 1 MB
    ws += (size_t)65536 * 8 * sizeof(_Float16);
    _Float16* b2pk = (_Float16*)ws;                         // 8 KB
    ws += (size_t)512 * 8 * sizeof(_Float16);
    float* wTih = (float*)ws;                               // 48 KB
    ws += (size_t)64 * 192 * sizeof(float);
    float* wThh = (float*)ws;                               // 48 KB
    ws += (size_t)64 * 192 * sizeof(float);
    float* agg = (float*)ws;                                // 6.4 MB

    prep_kernel<<<dim3(G_MS + G_PK + G_MLP), dim3(256), 0, stream>>>(
        W2, b2, w_ih, w_hh, edge_attr, W1, b1,
        Wpk, b2pk, wTih, wThh, hbuf, agg);

    edge_msg_mfma_kernel<<<dim3((N_EDGES + 63) / 64), dim3(256), 0, stream>>>(
        hbuf, x, edge_index, Wpk, b2pk, agg);

    gru_kernel<<<dim3((N_NODES + 31) / 32), dim3(256), 0, stream>>>(
        agg, x, wTih, wThh, b_ih, b_hh, out);
}